// Round 1
// 121.668 us; speedup vs baseline: 1.0332x; 1.0332x over previous
//
#include <hip/hip_runtime.h>
#include <math.h>

#define BLOCK 256
#define NN 100
#define HALF 50
#define GB 10           // boxes per pass-B block
#define NGRP (NN / GB)  // 10 box-groups per image
#define SPLIT 16        // anchor-dimension splits for pass B

__device__ __forceinline__ float fast_rcp(float x) { return __builtin_amdgcn_rcpf(x); }

// ---------------------------------------------------------------------------
// iou ordering identity: iou = I/(A+S-I) is monotone in t = I/(A+S) (t<1),
// and cross-multiplying t drops the "-inter" term:
//   iou_1 > iou_2  <=>  I_1*(A+S_2) > I_2*(A+S_1)
// so best state is (inter, s=A+S) -- one fewer op/pair and the compare is a
// single-rounding fma difference (more accurate than two rounded products).
//
// Fused match kernel:
//  blocks [0, NBB)        : pass B -- per-box partial column max over a
//                           4096-anchor slab, 10 boxes/block (long blocks
//                           first so the drain tail is short pass-A blocks).
//  blocks [NBB, NBB+NAB)  : pass A -- per-anchor row max over 100 boxes,
//                           two independent chains for ILP.
// ---------------------------------------------------------------------------
__global__ void __launch_bounds__(BLOCK, 4) bbp_fused(
    const float* __restrict__ anchors,            // [A,4] cbox (cx,cy,w,h)
    const float* __restrict__ bboxes,             // [B,N,4] bbox
    float2* __restrict__ pa,                      // [B*A] (row max iou, idx-as-float)
    unsigned long long* __restrict__ packed_part, // [B,N,SPLIT]
    int A, int NA, int NBB) {
    const int bid = blockIdx.x;
    const int tid = threadIdx.x;

    if (bid < NBB) {
        // ========== pass B: per-box partial max over one anchor slab ========
        const int b   = bid / (NGRP * SPLIT);
        const int rem = bid - b * (NGRP * SPLIT);
        const int ng  = rem / SPLIT;
        const int sp  = rem - ng * SPLIT;
        const int n0  = ng * GB;
        const int SA  = A / SPLIT;                // 4096 anchors per slab
        const int abase = sp * SA;
        const float* bb = bboxes + ((size_t)b * NN + n0) * 4;

        float bx1[GB], by1[GB], bx2[GB], by2[GB], sa[GB];
        #pragma unroll
        for (int g = 0; g < GB; ++g) {
            float4 v = *(const float4*)(bb + 4 * g);     // uniform -> s_load
            bx1[g] = v.x; by1[g] = v.y; bx2[g] = v.z; by2[g] = v.w;
            sa[g] = (v.z - v.x) * (v.w - v.y);
        }
        float cin[GB], cs[GB];
        int cai[GB];
        #pragma unroll
        for (int g = 0; g < GB; ++g) { cin[g] = -1.0f; cs[g] = 1.0f; cai[g] = abase + tid; }

        const int iters = SA >> 8;                       // 16
        #pragma unroll 4
        for (int j = 0; j < iters; ++j) {
            const int a = abase + j * BLOCK + tid;
            const float4 ac = *(const float4*)(anchors + (size_t)a * 4); // coalesced
            const float ax1 = fmaf(ac.z, -0.5f, ac.x);
            const float ay1 = fmaf(ac.w, -0.5f, ac.y);
            const float ax2 = fmaf(ac.z, 0.5f, ac.x);
            const float ay2 = fmaf(ac.w, 0.5f, ac.y);
            const float area_a = ac.z * ac.w;
            #pragma unroll
            for (int g = 0; g < GB; ++g) {
                float s  = area_a + sa[g];
                float lx = fmaxf(ax1, bx1[g]), ly = fmaxf(ay1, by1[g]);
                float rx = fminf(ax2, bx2[g]), ry = fminf(ay2, by2[g]);
                float w = fmaxf(rx - lx, 0.0f), h = fmaxf(ry - ly, 0.0f);
                float inter = w * h;
                float p2 = cin[g] * s;
                // strict >: smallest anchor wins ties
                if (fmaf(inter, cs[g], -p2) > 0.0f) { cin[g] = inter; cs[g] = s; cai[g] = a; }
            }
        }

        // once-per-block combine: shfl-u64 wave reduce -> LDS -> plain store
        __shared__ unsigned long long sred[GB][BLOCK / 64];
        #pragma unroll
        for (int g = 0; g < GB; ++g) {
            float iou = fmaxf(cin[g] * fast_rcp(cs[g] - cin[g]), 0.0f);
            unsigned long long pk =
                ((unsigned long long)__float_as_uint(iou) << 32)
                | (unsigned long long)(0xFFFFFFFFu - (unsigned)cai[g]);
            #pragma unroll
            for (int off = 32; off > 0; off >>= 1) {
                unsigned long long o = __shfl_down(pk, off, 64);
                if (o > pk) pk = o;
            }
            if ((tid & 63) == 0) sred[g][tid >> 6] = pk;
        }
        __syncthreads();
        if (tid < GB) {
            unsigned long long m = sred[tid][0];
            #pragma unroll
            for (int j = 1; j < BLOCK / 64; ++j) {
                unsigned long long o = sred[tid][j];
                if (o > m) m = o;
            }
            packed_part[((size_t)b * NN + n0 + tid) * SPLIT + sp] = m;
        }
    } else {
        // ========== pass A: per-anchor max/argmax over boxes ================
        const int abid = bid - NBB;
        const int b = abid / NA;
        const int a = (abid - b * NA) * BLOCK + tid;

        __shared__ float sarea[NN];
        if (tid < NN) {
            float4 v = *(const float4*)(bboxes + ((size_t)b * NN + tid) * 4);
            sarea[tid] = (v.z - v.x) * (v.w - v.y);
        }
        __syncthreads();

        const float4 ac = *(const float4*)(anchors + (size_t)a * 4);
        const float ax1 = fmaf(ac.z, -0.5f, ac.x);
        const float ay1 = fmaf(ac.w, -0.5f, ac.y);
        const float ax2 = fmaf(ac.z, 0.5f, ac.x);
        const float ay2 = fmaf(ac.w, 0.5f, ac.y);
        const float area_a = ac.z * ac.w;
        const float* bbase = bboxes + (size_t)b * NN * 4;   // wave-uniform

        // two independent chains (boxes 0..49 and 50..99) for ILP
        float in0 = -1.0f, s0 = 1.0f; int i0 = 0;
        float in1 = -1.0f, s1 = 1.0f; int i1 = HALF;
        #pragma unroll 5
        for (int n = 0; n < HALF; ++n) {
            {
                const float4 v = *(const float4*)(bbase + 4 * n);   // s_load
                const float s = area_a + sarea[n];
                float lx = fmaxf(ax1, v.x), ly = fmaxf(ay1, v.y);
                float rx = fminf(ax2, v.z), ry = fminf(ay2, v.w);
                float w = fmaxf(rx - lx, 0.0f), h = fmaxf(ry - ly, 0.0f);
                float inter = w * h;
                float p2 = in0 * s;
                if (fmaf(inter, s0, -p2) > 0.0f) { in0 = inter; s0 = s; i0 = n; }
            }
            {
                const int m = n + HALF;
                const float4 v = *(const float4*)(bbase + 4 * m);
                const float s = area_a + sarea[m];
                float lx = fmaxf(ax1, v.x), ly = fmaxf(ay1, v.y);
                float rx = fminf(ax2, v.z), ry = fminf(ay2, v.w);
                float w = fmaxf(rx - lx, 0.0f), h = fmaxf(ry - ly, 0.0f);
                float inter = w * h;
                float p2 = in1 * s;
                if (fmaf(inter, s1, -p2) > 0.0f) { in1 = inter; s1 = s; i1 = m; }
            }
        }
        // merge: chain0 (lower indices) wins exact ties -> first-occurrence
        {
            float p2 = in0 * s1;
            if (fmaf(in1, s0, -p2) > 0.0f) { in0 = in1; s0 = s1; i0 = i1; }
        }
        const size_t idx = (size_t)b * A + a;
        float2 r;
        r.x = in0 * fast_rcp(s0 - in0);   // reconstruct true iou once
        r.y = __int_as_float(i0);
        pa[idx] = r;
    }
}

// ---------------------------------------------------------------------------
// Finalize (absorbs the old combine kernel): each block redundantly reduces
// the SPLIT partials for all 100 boxes of its image in LDS (L2-hot, 12.8 KB
// per image), does the override scatter via LDS atomicMax, stages labels and
// boxes in LDS, then scores + encodes its 256 anchors.
// ---------------------------------------------------------------------------
__global__ void __launch_bounds__(BLOCK) bbp_finalize(
    const float* __restrict__ anchors, const float* __restrict__ bboxes,
    const int* __restrict__ labels, const float* __restrict__ mean4,
    const float* __restrict__ std4, const float* __restrict__ thr_p,
    const float2* __restrict__ pa,
    const unsigned long long* __restrict__ packed_part,
    float* __restrict__ out_conf, float* __restrict__ out_deltas,
    int A, int C) {
    const int b = blockIdx.y;
    const int tid = threadIdx.x;

    __shared__ float smax[NN];    // max_iou_of_bbox
    __shared__ float4 sbox[NN];   // gt boxes
    __shared__ int slab[NN];      // labels
    __shared__ int sovr[BLOCK];   // override winner per local anchor (-1 none)
    sovr[tid] = -1;
    __syncthreads();
    if (tid < NN) {
        const ulonglong2* pp =
            (const ulonglong2*)(packed_part + ((size_t)b * NN + tid) * SPLIT);
        unsigned long long m = 0;
        #pragma unroll
        for (int j = 0; j < SPLIT / 2; ++j) {
            ulonglong2 v = pp[j];
            if (v.x > m) m = v.x;
            if (v.y > m) m = v.y;
        }
        smax[tid] = __uint_as_float((unsigned)(m >> 32));
        unsigned an = 0xFFFFFFFFu - (unsigned)(m & 0xFFFFFFFFull);
        // segment_max over target ids: larger n wins -> atomicMax
        if ((an >> 8) == (unsigned)blockIdx.x)
            atomicMax(&sovr[an & (BLOCK - 1)], tid);
        slab[tid] = labels[(size_t)b * NN + tid];
        sbox[tid] = *(const float4*)(bboxes + ((size_t)b * NN + tid) * 4);
    }
    __syncthreads();

    const int a = blockIdx.x * BLOCK + tid;
    const size_t idx = (size_t)b * A + a;
    const float thr = thr_p[0];

    float2 pav = pa[idx];
    int ov = sovr[tid];
    bool valid = ov >= 0;
    int bi = valid ? ov : __float_as_int(pav.y);
    float mb = smax[bi];                      // max_iou_of_bbox[bi]
    float miou = valid ? mb : pav.x;
    float denom = fmaxf(mb, thr);
    if (miou < 0.5f * thr) miou = 0.0f;
    float score = miou * fast_rcp(denom);
    int lab = slab[bi];
    if (lab <= 0) { score = 0.0f; lab = 0; }

    for (int c = 0; c < C; ++c)
        out_conf[idx * (size_t)C + c] = (lab == c + 1) ? score : 0.0f;

    float4 bv = sbox[bi];
    float4 av = *(const float4*)(anchors + (size_t)a * 4);
    float cx = (bv.x + bv.z) * 0.5f;
    float cy = (bv.y + bv.w) * 0.5f;
    float bw = bv.z - bv.x;
    float bh = bv.w - bv.y;
    const float rz = fast_rcp(av.z), rw = fast_rcp(av.w);
    float4 d;
    d.x = ((cx - av.x) * rz - mean4[0]) * fast_rcp(std4[0]);
    d.y = ((cy - av.y) * rw - mean4[1]) * fast_rcp(std4[1]);
    d.z = (__logf(bw * rz) - mean4[2]) * fast_rcp(std4[2]);
    d.w = (__logf(bh * rw) - mean4[3]) * fast_rcp(std4[3]);
    *(float4*)(out_deltas + idx * 4) = d;
}

// ---------------------------------------------------------------------------
extern "C" void kernel_launch(void* const* d_in, const int* in_sizes, int n_in,
                              void* d_out, int out_size, void* d_ws, size_t ws_size,
                              hipStream_t stream) {
    const float* anchors = (const float*)d_in[0];
    const int* labels = (const int*)d_in[1];
    const float* bboxes = (const float*)d_in[2];
    const float* mean4 = (const float*)d_in[3];
    const float* std4 = (const float*)d_in[4];
    const float* thr_p = (const float*)d_in[5];

    const int A = in_sizes[0] / 4;        // 65536
    const int BN = in_sizes[1];           // 800
    const int B = BN / NN;                // 8
    const int C = out_size / (B * A) - 4; // 1
    const int NA = A / BLOCK;             // 256 pass-A block-groups per image
    const int NAB = B * NA;               // 2048 pass-A blocks
    const int NBB = B * NGRP * SPLIT;     // 1280 pass-B blocks

    char* ws = (char*)d_ws;
    unsigned long long* packed_part = (unsigned long long*)ws;        // [B*N*SPLIT]
    size_t off = ((size_t)B * NN * SPLIT * sizeof(unsigned long long) + 255) & ~(size_t)255;
    float2* pa = (float2*)(ws + off);                                 // [B*A]

    float* out_conf = (float*)d_out;
    float* out_deltas = out_conf + (size_t)B * A * C;

    bbp_fused<<<dim3(NBB + NAB), dim3(BLOCK), 0, stream>>>(
        anchors, bboxes, pa, packed_part, A, NA, NBB);

    bbp_finalize<<<dim3(A / BLOCK, B), dim3(BLOCK), 0, stream>>>(
        anchors, bboxes, labels, mean4, std4, thr_p, pa, packed_part,
        out_conf, out_deltas, A, C);
}